// Round 9
// baseline (298.518 us; speedup 1.0000x reference)
//
#include <hip/hip_runtime.h>
#include <math.h>

#define BB 2
#define NF 20000
#define NS 30000
#define CH 128
#define NK 500
#define KNN 16
#define KPB 4

// grid params: cell = 1.001 * radius (margin vs float boundary rounding)
#define HA 2.4024f
#define HB 4.8048f
#define NCA 45
#define NCB 23
#define CELLS_A 2025
#define CELLS_B 529

// output offsets (floats, concatenated in return order)
#define OUT0_OFF 0           // out          (B*NK*128) = 128000
#define OUT1_OFF 128000      // key_voxel_indices (B*NK*3) = 3000
#define OUT2_OFF 131000      // heat_scores  (B*NF) = 40000
#define OUT3_OFF 171000      // scores10     (B*NF*10) = 400000
#define OUT4_OFF 571000      // key_class    (B*NK) = 1000

// workspace offsets (bytes)
#define WS_CLS   0           // int32  x 40000
#define WS_TKI   160000      // int32  x 1000
#define WS_KW    164000      // float  x 2000
#define WS_MF    172000      // float  x 256000 (1,024,000 B)
#define WS_KEYS  WS_MF       // u64 x 40000 overlays mf (temporally disjoint)
#define WS_GSTART 1196000    // int x 5112 (cell starts, +1 per (s,b))
#define WS_PTS    1236880    // float2 x 120000 (sorted world coords)
#define WS_PIDX   2196880    // int x 120000 (sorted original indices)

#define STB(s,b)  ((s) ? (4052 + (b) * 530) : ((b) * 2026))

#define HEATBLKS 625   // (BB*NF)/64

__device__ __forceinline__ void fma4(float4& acc, float sc, const float4& wv) {
    acc.x += sc * wv.x; acc.y += sc * wv.y;
    acc.z += sc * wv.z; acc.w += sc * wv.w;
}

__device__ __forceinline__ unsigned ordf(float s) {
    unsigned u = __float_as_uint(s);
    return (u & 0x80000000u) ? ~u : (u | 0x80000000u);
}

__device__ __forceinline__ void world_cell_sb(
    const int2* sc, int s, int i, float& sx, float& sy, int& cell)
{
    int2 c = sc[i];
    float stride = s ? 8.0f : 4.0f;
    sx = __fadd_rn(__fmul_rn(__fmul_rn(__fadd_rn((float)c.x, 0.5f), stride), 0.075f), -54.0f);
    sy = __fadd_rn(__fmul_rn(__fmul_rn(__fadd_rn((float)c.y, 0.5f), stride), 0.075f), -54.0f);
    float inv_h = s ? (1.0f / HB) : (1.0f / HA);
    int nc = s ? NCB : NCA;
    int cx = (int)floorf((sx + 54.0f) * inv_h);
    int cy = (int)floorf((sy + 54.0f) * inv_h);
    cx = min(max(cx, 0), nc - 1);
    cy = min(max(cy, 0), nc - 1);
    cell = cy * nc + cx;
}

// ---------------------------------------------------------------------------
// K1: heat MLP (blocks 0..624) + spatial grid build (blocks 625..628).
// Grid build is independent of heat outputs -> runs on idle CUs for free.
// ---------------------------------------------------------------------------
__global__ __launch_bounds__(256) void heat_kernel(
    const float* __restrict__ x,
    const float* __restrict__ w1,
    const float* __restrict__ g1, const float* __restrict__ b1,
    const float* __restrict__ w2,
    const float* __restrict__ b2,
    float* __restrict__ out_heat,
    float* __restrict__ out_s10,
    int* __restrict__ cls,
    unsigned long long* __restrict__ keys,
    const int* __restrict__ sca, const int* __restrict__ scb,
    int* __restrict__ gstart,
    float2* __restrict__ pts, int* __restrict__ pidx)
{
    __shared__ float As[64 * 72];
    __shared__ float Ws[64 * 132];
    __shared__ float W2s[1280];
    const int tid = threadIdx.x;

    if (blockIdx.x >= HEATBLKS) {
        // ---- grid build for (s,b), 256 threads ----
        const int g = blockIdx.x - HEATBLKS;
        const int s = g >> 1, b = g & 1;
        const int n = s ? CELLS_B : CELLS_A;
        const int stb = STB(s, b);
        const int2* sc = ((const int2*)(s ? scb : sca)) + (size_t)b * NS;
        const size_t pbase = ((size_t)s * BB + b) * NS;
        int* ghist = (int*)As;          // 2048 ints
        int* ct  = (int*)Ws;            // 256 ints
        int* ct2 = ((int*)Ws) + 256;    // 256 ints

        for (int i = tid; i < 2048; i += 256) ghist[i] = 0;
        __syncthreads();
        for (int i = tid; i < NS; i += 256) {
            float sx, sy; int cell;
            world_cell_sb(sc, s, i, sx, sy, cell);
            atomicAdd(&ghist[cell], 1);
        }
        __syncthreads();
        // scan: thread owns 8 cells
        const int base = tid * 8;
        int loc[8]; int csum8 = 0;
#pragma unroll
        for (int j = 0; j < 8; ++j) { loc[j] = ghist[base + j]; csum8 += loc[j]; }
        ct[tid] = csum8;
        __syncthreads();
        int* srcp = ct; int* dstp = ct2;
        for (int off = 1; off < 256; off <<= 1) {
            int v = srcp[tid];
            if (tid >= off) v += srcp[tid - off];
            dstp[tid] = v;
            __syncthreads();
            int* t = srcp; srcp = dstp; dstp = t;
        }
        int excl = (tid == 0) ? 0 : srcp[tid - 1];
        __syncthreads();
#pragma unroll
        for (int j = 0; j < 8; ++j) {
            if (base + j < n) gstart[stb + base + j] = excl;
            ghist[base + j] = excl;
            excl += loc[j];
        }
        if (tid == 0) gstart[stb + n] = NS;
        __syncthreads();
        for (int i = tid; i < NS; i += 256) {
            float sx, sy; int cell;
            world_cell_sb(sc, s, i, sx, sy, cell);
            int pos = atomicAdd(&ghist[cell], 1);
            pts[pbase + pos] = make_float2(sx, sy);
            pidx[pbase + pos] = i;
        }
        return;
    }

    // ---- heat MLP tile ----
    const int m0 = blockIdx.x * 64;
    const int tx = tid & 15;
    const int ty = tid >> 4;

    for (int v = tid; v < 1280; v += 256) W2s[v] = w2[v];

    float acc[4][8];
#pragma unroll
    for (int i = 0; i < 4; ++i)
#pragma unroll
        for (int j = 0; j < 8; ++j) acc[i][j] = 0.f;

    const float4* xv = (const float4*)x;
    const float4* w1v = (const float4*)w1;

    for (int kc = 0; kc < 128; kc += 64) {
#pragma unroll
        for (int i = 0; i < 4; ++i) {
            int v = tid + i * 256;
            int row = v >> 4, c4 = v & 15;
            float4 val = xv[(size_t)(m0 + row) * 32 + (kc >> 2) + c4];
            *(float4*)&As[row * 72 + c4 * 4] = val;
        }
#pragma unroll
        for (int i = 0; i < 8; ++i) {
            int v = tid + i * 256;
            int k = v >> 5, c4 = v & 31;
            float4 val = w1v[(size_t)(kc + k) * 32 + c4];
            *(float4*)&Ws[k * 132 + c4 * 4] = val;
        }
        __syncthreads();

        const float* a0p = &As[(ty * 4 + 0) * 72];
        const float* a1p = &As[(ty * 4 + 1) * 72];
        const float* a2p = &As[(ty * 4 + 2) * 72];
        const float* a3p = &As[(ty * 4 + 3) * 72];
#pragma unroll 4
        for (int k = 0; k < 64; ++k) {
            float4 bA = *(const float4*)&Ws[k * 132 + tx * 8];
            float4 bB = *(const float4*)&Ws[k * 132 + tx * 8 + 4];
            float a0 = a0p[k], a1 = a1p[k], a2 = a2p[k], a3 = a3p[k];
            acc[0][0] += a0 * bA.x; acc[0][1] += a0 * bA.y; acc[0][2] += a0 * bA.z; acc[0][3] += a0 * bA.w;
            acc[0][4] += a0 * bB.x; acc[0][5] += a0 * bB.y; acc[0][6] += a0 * bB.z; acc[0][7] += a0 * bB.w;
            acc[1][0] += a1 * bA.x; acc[1][1] += a1 * bA.y; acc[1][2] += a1 * bA.z; acc[1][3] += a1 * bA.w;
            acc[1][4] += a1 * bB.x; acc[1][5] += a1 * bB.y; acc[1][6] += a1 * bB.z; acc[1][7] += a1 * bB.w;
            acc[2][0] += a2 * bA.x; acc[2][1] += a2 * bA.y; acc[2][2] += a2 * bA.z; acc[2][3] += a2 * bA.w;
            acc[2][4] += a2 * bB.x; acc[2][5] += a2 * bB.y; acc[2][6] += a2 * bB.z; acc[2][7] += a2 * bB.w;
            acc[3][0] += a3 * bA.x; acc[3][1] += a3 * bA.y; acc[3][2] += a3 * bA.z; acc[3][3] += a3 * bA.w;
            acc[3][4] += a3 * bB.x; acc[3][5] += a3 * bB.y; acc[3][6] += a3 * bB.z; acc[3][7] += a3 * bB.w;
        }
        __syncthreads();
    }

    float4 g1a = ((const float4*)g1)[tx * 2], g1b = ((const float4*)g1)[tx * 2 + 1];
    float4 b1a = ((const float4*)b1)[tx * 2], b1b = ((const float4*)b1)[tx * 2 + 1];
    float* Hs = Ws;
#pragma unroll
    for (int i = 0; i < 4; ++i) {
        int row = ty * 4 + i;
        float4 hA, hB;
        hA.x = fmaxf(acc[i][0] * g1a.x + b1a.x, 0.f);
        hA.y = fmaxf(acc[i][1] * g1a.y + b1a.y, 0.f);
        hA.z = fmaxf(acc[i][2] * g1a.z + b1a.z, 0.f);
        hA.w = fmaxf(acc[i][3] * g1a.w + b1a.w, 0.f);
        hB.x = fmaxf(acc[i][4] * g1b.x + b1b.x, 0.f);
        hB.y = fmaxf(acc[i][5] * g1b.y + b1b.y, 0.f);
        hB.z = fmaxf(acc[i][6] * g1b.z + b1b.z, 0.f);
        hB.w = fmaxf(acc[i][7] * g1b.w + b1b.w, 0.f);
        *(float4*)&Hs[row * 132 + tx * 8] = hA;
        *(float4*)&Hs[row * 132 + tx * 8 + 4] = hB;
    }
    __syncthreads();

    const int r = tid >> 2;
    const int p = tid & 3;
    float a2[10];
#pragma unroll
    for (int c = 0; c < 10; ++c) a2[c] = 0.f;
    for (int kk = 0; kk < 32; ++kk) {
        int k = kk * 4 + p;
        float hv = Hs[r * 132 + k];
#pragma unroll
        for (int c = 0; c < 10; ++c) a2[c] += hv * W2s[k * 10 + c];
    }
#pragma unroll
    for (int c = 0; c < 10; ++c) {
        a2[c] += __shfl_xor(a2[c], 1);
        a2[c] += __shfl_xor(a2[c], 2);
    }
    if (p == 0) {
        int m = m0 + r;
        float best = -INFINITY;
        int bi = 0;
#pragma unroll
        for (int c = 0; c < 10; ++c) {
            float s = a2[c] + b2[c];
            out_s10[(size_t)m * 10 + c] = s;
            if (s > best) { best = s; bi = c; }
        }
        out_heat[m] = best;
        cls[m] = bi;
        int b = m / NF;
        unsigned i = (unsigned)(m - b * NF);
        float sig = 1.0f / (1.0f + expf(-best));
        keys[m] = ((unsigned long long)ordf(sig) << 32) | (unsigned)(~i);
    }
}

// ---------------------------------------------------------------------------
// K2: exact top-500 per batch. Parallel suffix-scan threshold finding +
// exhaustive rank-by-comparison (no bitonic sort, no serial LDS scans).
// ---------------------------------------------------------------------------
#define H1BINS 16384

__global__ __launch_bounds__(1024) void topk_kernel(
    const unsigned long long* __restrict__ keys,
    const int* __restrict__ cls,
    const int* __restrict__ fcoords,
    float* __restrict__ out1,
    float* __restrict__ out4,
    int* __restrict__ tki,
    float* __restrict__ keyworld)
{
    __shared__ unsigned h[H1BINS];            // 64 KB
    __shared__ unsigned sA[1024], sB[1024];   // 8 KB scan buffers
    __shared__ unsigned long long list[1024]; // 8 KB
    __shared__ unsigned chunk_s, aboveC_s, T1_s, aboveT1_s, cand_s, thr_s, cnt_s;
    const int b = blockIdx.x;
    const int tid = threadIdx.x;
    const unsigned long long* kb = keys + (size_t)b * NF;
    const unsigned K = NK;

    for (int i = tid; i < H1BINS; i += 1024) h[i] = 0u;
    __syncthreads();
#pragma unroll 4
    for (int i = tid; i < NF; i += 1024)
        atomicAdd(&h[(unsigned)(kb[i] >> 50)], 1u);
    __syncthreads();
    unsigned ck = 0;
    {
        int base = tid * 16;
#pragma unroll
        for (int j = 0; j < 16; ++j) ck += h[base + j];
        sA[tid] = ck;
    }
    __syncthreads();
    // inclusive suffix scan over 1024 chunk sums
    unsigned* srcp = sA; unsigned* dstp = sB;
    for (int off = 1; off < 1024; off <<= 1) {
        unsigned v = srcp[tid];
        if (tid + off < 1024) v += srcp[tid + off];
        dstp[tid] = v;
        __syncthreads();
        unsigned* t = srcp; srcp = dstp; dstp = t;
    }
    {
        unsigned suf = srcp[tid];
        unsigned above = suf - ck;
        if (above < K && K <= suf) { chunk_s = (unsigned)tid; aboveC_s = above; }
    }
    __syncthreads();
    if (tid == 0) {
        int bin = (int)chunk_s * 16 + 15;
        unsigned acc = aboveC_s;
        for (;; --bin) { if (acc + h[bin] >= K) break; acc += h[bin]; }
        T1_s = (unsigned)bin;
        aboveT1_s = acc;
        cand_s = acc + h[bin];
        cnt_s = 0u;
    }
    __syncthreads();
    const unsigned T1 = T1_s;

    if (cand_s <= 1024u) {
        // direct collect with 14-bit threshold (the common path)
#pragma unroll 4
        for (int i = tid; i < NF; i += 1024) {
            unsigned long long key = kb[i];
            if ((unsigned)(key >> 50) >= T1) {
                unsigned pos = atomicAdd(&cnt_s, 1u);
                if (pos < 1024u) list[pos] = key;
            }
        }
    } else {
        // fallback: refine to 24-bit threshold (rare: >1024 keys in one bin)
        const unsigned K2 = K - aboveT1_s;
        h[tid] = 0u;
        __syncthreads();
#pragma unroll 4
        for (int i = tid; i < NF; i += 1024) {
            unsigned long long key = kb[i];
            if ((unsigned)(key >> 50) == T1)
                atomicAdd(&h[(unsigned)(key >> 40) & 1023u], 1u);
        }
        __syncthreads();
        unsigned hb = h[tid];
        sA[tid] = hb;
        __syncthreads();
        unsigned* s2 = sA; unsigned* d2 = sB;
        for (int off = 1; off < 1024; off <<= 1) {
            unsigned v = s2[tid];
            if (tid + off < 1024) v += s2[tid + off];
            d2[tid] = v;
            __syncthreads();
            unsigned* t = s2; s2 = d2; d2 = t;
        }
        {
            unsigned suf = s2[tid];
            unsigned above = suf - hb;
            if (above < K2 && K2 <= suf) thr_s = (T1 << 10) | (unsigned)tid;
        }
        __syncthreads();
        const unsigned thr24 = thr_s;
#pragma unroll 4
        for (int i = tid; i < NF; i += 1024) {
            unsigned long long key = kb[i];
            if ((unsigned)(key >> 40) >= thr24) {
                unsigned pos = atomicAdd(&cnt_s, 1u);
                if (pos < 1024u) list[pos] = key;
            }
        }
    }
    __syncthreads();
    const int cc = (int)(cnt_s > 1024u ? 1024u : cnt_s);

    // exhaustive ranking: keys unique -> exact permutation, no barriers
    if (tid < cc) {
        unsigned long long mykey = list[tid];
        unsigned r = 0;
#pragma unroll 8
        for (int j = 0; j < cc; ++j) r += (list[j] > mykey) ? 1u : 0u;
        if (r < (unsigned)NK) {
            int idx = (int)(~(unsigned)(mykey & 0xFFFFFFFFull));
            tki[b * NK + (int)r] = idx;
            int c0 = fcoords[((size_t)b * NF + idx) * 2 + 0];
            int c1 = fcoords[((size_t)b * NF + idx) * 2 + 1];
            size_t o = (size_t)(b * NK + (int)r);
            out1[o * 3 + 0] = (float)b;
            out1[o * 3 + 1] = (float)c0;
            out1[o * 3 + 2] = (float)c1;
            float wx = __fadd_rn(__fmul_rn(__fmul_rn(__fadd_rn((float)c0, 0.5f), 8.0f), 0.075f), -54.0f);
            float wy = __fadd_rn(__fmul_rn(__fmul_rn(__fadd_rn((float)c1, 0.5f), 8.0f), 0.075f), -54.0f);
            keyworld[o * 2 + 0] = wx;
            keyworld[o * 2 + 1] = wy;
            out4[o] = (float)cls[(size_t)b * NF + idx];
        }
    }
}

// ---------------------------------------------------------------------------
// K3: grid-accelerated radius-KNN (unchanged).
// ---------------------------------------------------------------------------
__global__ __launch_bounds__(256) void knn_kernel(
    const float* __restrict__ sfa, const float* __restrict__ sfb,
    const int* __restrict__ gstart,
    const float2* __restrict__ pts, const int* __restrict__ pidx,
    const float* __restrict__ knn_w,
    const float* __restrict__ knn_b,
    const float* __restrict__ keyworld,
    float* __restrict__ mf)
{
    __shared__ unsigned long long list[1024];
    __shared__ float psum[128];
    __shared__ unsigned cnt_s;
    const int tid = threadIdx.x;
    const int blk = blockIdx.x;
    const int s = blk / (BB * NK);
    const int rest = blk % (BB * NK);
    const int b = rest / NK;
    const int r = rest % NK;
    const float* sfeat = s ? sfb : sfa;
    const float r2 = s ? (float)(4.8 * 4.8) : (float)(2.4 * 2.4);
    const float inv_h = s ? (1.0f / HB) : (1.0f / HA);
    const int nc = s ? NCB : NCA;
    const int stb = STB(s, b);
    const size_t pbase = ((size_t)s * BB + b) * NS;

    if (tid == 0) cnt_s = 0u;
    __syncthreads();
    const float kx = keyworld[((size_t)b * NK + r) * 2 + 0];
    const float ky = keyworld[((size_t)b * NK + r) * 2 + 1];
    int cx = (int)floorf((kx + 54.0f) * inv_h);
    int cy = (int)floorf((ky + 54.0f) * inv_h);
    cx = min(max(cx, 0), nc - 1);
    cy = min(max(cy, 0), nc - 1);
    const int c0 = max(cx - 1, 0), c1 = min(cx + 1, nc - 1);
    const int cy0 = max(cy - 1, 0), cy1 = min(cy + 1, nc - 1);

    for (int cyy = cy0; cyy <= cy1; ++cyy) {
        int lo = gstart[stb + cyy * nc + c0];
        int hi = gstart[stb + cyy * nc + c1 + 1];
        for (int p = lo + tid; p < hi; p += 256) {
            float2 w = pts[pbase + p];
            float dx = __fsub_rn(kx, w.x);
            float dy = __fsub_rn(ky, w.y);
            float d2 = __fadd_rn(__fmul_rn(dx, dx), __fmul_rn(dy, dy));
            if (d2 <= r2) {
                unsigned pos = atomicAdd(&cnt_s, 1u);
                if (pos < 1024u)
                    list[pos] = ((unsigned long long)__float_as_uint(d2) << 32)
                              | (unsigned)pidx[pbase + p];
            }
        }
    }
    __syncthreads();
    int cc = (int)cnt_s;
    if (cc > 1024) cc = 1024;
    int n2 = 16;
    while (n2 < cc) n2 <<= 1;
    for (int i = tid; i < n2; i += 256)
        if (i >= cc) list[i] = ~0ull;
    __syncthreads();
    for (int kk = 2; kk <= n2; kk <<= 1) {
        for (int j = kk >> 1; j > 0; j >>= 1) {
            for (int i = tid; i < n2; i += 256) {
                int ixj = i ^ j;
                if (ixj > i) {
                    unsigned long long a = list[i], bv = list[ixj];
                    bool up = ((i & kk) == 0);
                    bool sw = up ? (a > bv) : (a < bv);
                    if (sw) { list[i] = bv; list[ixj] = a; }
                }
            }
            __syncthreads();
        }
    }
    {
        int K = cc < KNN ? cc : KNN;
        int col = tid & 127, half = tid >> 7;
        float acc = 0.f;
        int k0 = half * 8, k1 = min(K, half * 8 + 8);
        for (int k = k0; k < k1; ++k) {
            unsigned i = (unsigned)(list[k] & 0xFFFFFFFFull);
            acc += knn_w[s * 16 + k] * sfeat[((size_t)b * NS + i) * CH + col];
        }
        if (half) psum[col] = acc;
        __syncthreads();
        if (!half)
            mf[(((size_t)s * BB + b) * NK + r) * CH + col] = knn_b[s] + acc + psum[col];
    }
}

// ---------------------------------------------------------------------------
// K4: fuse MLP (unchanged from R8: direct L2-resident float4 weight loads,
// 8-16 in flight, transposed activations, split-K tree reduce).
// ---------------------------------------------------------------------------
__global__ __launch_bounds__(1024) void fuse_kernel(
    const float* __restrict__ ffeat,
    const int* __restrict__ tki,
    const float* __restrict__ kw_w1, const float* __restrict__ kw_g1,
    const float* __restrict__ kw_b1, const float* __restrict__ kw_w2,
    const float* __restrict__ kw_b2,
    const float* __restrict__ fuse_w1, const float* __restrict__ fuse_g1,
    const float* __restrict__ fuse_b1, const float* __restrict__ fuse_w2,
    const float* __restrict__ fuse_b2,
    const float* __restrict__ mf,
    float* __restrict__ out0)
{
    __shared__ float pL[16384];     // 64 KB split-K partials
    __shared__ float xsT[512];      // x transposed [k][key]
    __shared__ float mfs[1024];     // [src][key][c]
    __shared__ float fusedvT[1024]; // [k][key]
    __shared__ float h2sT[1024];    // [k][key]
    __shared__ float prm[964];      // kw_g1|kw_b1|kw_w2|kw_b2|fg1|fb1|fb2
    __shared__ float hsX[256];      // kw hidden [key][k]
    __shared__ float p2[96];
    __shared__ float l3[12];
    __shared__ float wsm[8];
    __shared__ int idxs[KPB], bs[KPB], rs[KPB];
    const int tid = threadIdx.x;
    const int f0 = blockIdx.x * KPB;

    if (tid < 964) {
        float v;
        if (tid < 64)       v = kw_g1[tid];
        else if (tid < 128) v = kw_b1[tid - 64];
        else if (tid < 320) v = kw_w2[tid - 128];
        else if (tid < 323) v = kw_b2[tid - 320];
        else if (tid < 324) v = 0.f;
        else if (tid < 580) v = fuse_g1[tid - 324];
        else if (tid < 836) v = fuse_b1[tid - 580];
        else                v = fuse_b2[tid - 836];
        prm[tid] = v;
    }
    if (tid < KPB) {
        int flat = f0 + tid;
        int b = flat / NK;
        bs[tid] = b;
        rs[tid] = flat - b * NK;
        idxs[tid] = tki[flat];
    }
    __syncthreads();

    if (tid < 128) {
        int key = tid >> 5, c4 = tid & 31;
        float4 v = ((const float4*)(ffeat + ((size_t)bs[key] * NF + idxs[key]) * CH))[c4];
        xsT[(c4 * 4 + 0) * 4 + key] = v.x;
        xsT[(c4 * 4 + 1) * 4 + key] = v.y;
        xsT[(c4 * 4 + 2) * 4 + key] = v.z;
        xsT[(c4 * 4 + 3) * 4 + key] = v.w;
    }
    if (tid < 256) {
        int ss = tid >> 7, key = (tid >> 5) & 3, c4 = tid & 31;
        float4 v = ((const float4*)(mf + (((size_t)ss * BB + bs[key]) * NK + rs[key]) * CH))[c4];
        *(float4*)&mfs[ss * 512 + key * 128 + c4 * 4] = v;
    }
    __syncthreads();

    if (tid < 256) {
        const int og = tid & 15, kseg = tid >> 4;
        float4 wr[8];
#pragma unroll
        for (int m = 0; m < 8; ++m)
            wr[m] = ((const float4*)kw_w1)[(kseg * 8 + m) * 16 + og];
        float4 a0 = {0, 0, 0, 0}, a1 = {0, 0, 0, 0}, a2 = {0, 0, 0, 0}, a3 = {0, 0, 0, 0};
#pragma unroll
        for (int m = 0; m < 8; ++m) {
            float4 f4 = *(const float4*)&xsT[(kseg * 8 + m) * 4];
            fma4(a0, f4.x, wr[m]);
            fma4(a1, f4.y, wr[m]);
            fma4(a2, f4.z, wr[m]);
            fma4(a3, f4.w, wr[m]);
        }
        *(float4*)&pL[(kseg * 4 + 0) * 64 + og * 4] = a0;
        *(float4*)&pL[(kseg * 4 + 1) * 64 + og * 4] = a1;
        *(float4*)&pL[(kseg * 4 + 2) * 64 + og * 4] = a2;
        *(float4*)&pL[(kseg * 4 + 3) * 64 + og * 4] = a3;
    }
    __syncthreads();
    if (tid < 256) {
        int out = tid >> 2, key = tid & 3;
        float s = 0.f;
#pragma unroll
        for (int ks = 0; ks < 16; ++ks) s += pL[(ks * 4 + key) * 64 + out];
        float t = s * prm[out] + prm[64 + out];
        hsX[key * 64 + out] = t > 0.f ? t : 0.f;
    }
    __syncthreads();
    if (tid < 96) {
        int key = tid / 24, rr = tid % 24, out = rr >> 3, seg = rr & 7;
        float acc = 0.f;
#pragma unroll
        for (int m = 0; m < 8; ++m) {
            int k = seg * 8 + m;
            acc += hsX[key * 64 + k] * prm[128 + k * 3 + out];
        }
        p2[(key * 3 + out) * 8 + seg] = acc;
    }
    __syncthreads();
    if (tid < 12) {
        int key = tid / 3, out = tid % 3;
        float s = 0.f;
#pragma unroll
        for (int j = 0; j < 8; ++j) s += p2[(key * 3 + out) * 8 + j];
        l3[key * 3 + out] = s + prm[320 + out];
    }
    __syncthreads();
    if (tid < KPB) {
        float l0 = l3[tid * 3], l1 = l3[tid * 3 + 1], l2 = l3[tid * 3 + 2];
        float m = fmaxf(l0, fmaxf(l1, l2));
        float e0 = expf(l0 - m), e1 = expf(l1 - m), e2 = expf(l2 - m);
        float sum = e0 + e1 + e2;
        wsm[tid * 2 + 0] = e0 / sum;
        wsm[tid * 2 + 1] = e1 / sum;
    }
    __syncthreads();

    {
        int c = tid >> 2, key = tid & 3;
        float w0 = wsm[key * 2], w1_ = wsm[key * 2 + 1];
        float val;
        if (c < 128) {
            float xv_ = xsT[c * 4 + key];
            float m0 = mfs[key * 128 + c];
            float m1 = mfs[512 + key * 128 + c];
            float kv = w0 * xv_;
            float kv2 = w1_ * kv;
            val = kv * m0 + kv2 * m1;
        } else {
            float xv_ = xsT[(c - 128) * 4 + key];
            val = w1_ * (w0 * xv_);
        }
        fusedvT[tid] = val;
    }
    __syncthreads();

    {
        const int og = tid & 63, kseg = tid >> 6;
        const float4* w1v = (const float4*)fuse_w1;
        float4 wr[16];
#pragma unroll
        for (int m = 0; m < 16; ++m)
            wr[m] = w1v[(kseg * 16 + m) * 64 + og];
        float4 a0 = {0, 0, 0, 0}, a1 = {0, 0, 0, 0}, a2 = {0, 0, 0, 0}, a3 = {0, 0, 0, 0};
#pragma unroll
        for (int m = 0; m < 16; ++m) {
            float4 f4 = *(const float4*)&fusedvT[(kseg * 16 + m) * 4];
            fma4(a0, f4.x, wr[m]);
            fma4(a1, f4.y, wr[m]);
            fma4(a2, f4.z, wr[m]);
            fma4(a3, f4.w, wr[m]);
        }
        *(float4*)&pL[(kseg * 4 + 0) * 256 + og * 4] = a0;
        *(float4*)&pL[(kseg * 4 + 1) * 256 + og * 4] = a1;
        *(float4*)&pL[(kseg * 4 + 2) * 256 + og * 4] = a2;
        *(float4*)&pL[(kseg * 4 + 3) * 256 + og * 4] = a3;
    }
    __syncthreads();
    {
        int out = tid >> 2, key = tid & 3;
        float s = 0.f;
#pragma unroll
        for (int ks = 0; ks < 16; ++ks) s += pL[(ks * 4 + key) * 256 + out];
        float t = s * prm[324 + out] + prm[580 + out];
        h2sT[out * 4 + key] = t > 0.f ? t : 0.f;
    }
    __syncthreads();

    {
        const int og2 = tid & 31, kseg2 = tid >> 5;
        const float4* w2v = (const float4*)fuse_w2;
        float4 wr[8];
#pragma unroll
        for (int m = 0; m < 8; ++m)
            wr[m] = w2v[(kseg2 * 8 + m) * 32 + og2];
        float4 a0 = {0, 0, 0, 0}, a1 = {0, 0, 0, 0}, a2 = {0, 0, 0, 0}, a3 = {0, 0, 0, 0};
#pragma unroll
        for (int m = 0; m < 8; ++m) {
            float4 f4 = *(const float4*)&h2sT[(kseg2 * 8 + m) * 4];
            fma4(a0, f4.x, wr[m]);
            fma4(a1, f4.y, wr[m]);
            fma4(a2, f4.z, wr[m]);
            fma4(a3, f4.w, wr[m]);
        }
        *(float4*)&pL[(kseg2 * 4 + 0) * 128 + og2 * 4] = a0;
        *(float4*)&pL[(kseg2 * 4 + 1) * 128 + og2 * 4] = a1;
        *(float4*)&pL[(kseg2 * 4 + 2) * 128 + og2 * 4] = a2;
        *(float4*)&pL[(kseg2 * 4 + 3) * 128 + og2 * 4] = a3;
    }
    __syncthreads();
    if (tid < 512) {
        int out = tid >> 2, key = tid & 3;
        float s = prm[836 + out];
#pragma unroll
        for (int ks = 0; ks < 32; ++ks) s += pL[(ks * 4 + key) * 128 + out];
        out0[((size_t)bs[key] * NK + rs[key]) * CH + out] = s;
    }
}

extern "C" void kernel_launch(void* const* d_in, const int* in_sizes, int n_in,
                              void* d_out, int out_size, void* d_ws, size_t ws_size,
                              hipStream_t stream)
{
    const float* fusion_feat = (const float*)d_in[0];
    const float* src_feat_a  = (const float*)d_in[1];
    const float* src_feat_b  = (const float*)d_in[2];
    const float* heat_w1 = (const float*)d_in[3];
    const float* heat_g1 = (const float*)d_in[4];
    const float* heat_b1 = (const float*)d_in[5];
    const float* heat_w2 = (const float*)d_in[6];
    const float* heat_b2 = (const float*)d_in[7];
    const float* knn_w   = (const float*)d_in[8];
    const float* knn_b   = (const float*)d_in[9];
    const float* kw_w1   = (const float*)d_in[10];
    const float* kw_g1   = (const float*)d_in[11];
    const float* kw_b1   = (const float*)d_in[12];
    const float* kw_w2   = (const float*)d_in[13];
    const float* kw_b2   = (const float*)d_in[14];
    const float* fuse_w1 = (const float*)d_in[15];
    const float* fuse_g1 = (const float*)d_in[16];
    const float* fuse_b1 = (const float*)d_in[17];
    const float* fuse_w2 = (const float*)d_in[18];
    const float* fuse_b2 = (const float*)d_in[19];
    const int* fusion_coords = (const int*)d_in[20];
    const int* src_coords_a  = (const int*)d_in[21];
    const int* src_coords_b  = (const int*)d_in[22];

    float* out = (float*)d_out;
    char* ws = (char*)d_ws;
    int* cls = (int*)(ws + WS_CLS);
    int* tki = (int*)(ws + WS_TKI);
    float* keyworld = (float*)(ws + WS_KW);
    float* mf = (float*)(ws + WS_MF);
    unsigned long long* keys = (unsigned long long*)(ws + WS_KEYS);
    int* gstart = (int*)(ws + WS_GSTART);
    float2* pts = (float2*)(ws + WS_PTS);
    int* pidx = (int*)(ws + WS_PIDX);

    heat_kernel<<<HEATBLKS + 4, 256, 0, stream>>>(
        fusion_feat, heat_w1, heat_g1, heat_b1, heat_w2, heat_b2,
        out + OUT2_OFF, out + OUT3_OFF, cls, keys,
        src_coords_a, src_coords_b, gstart, pts, pidx);

    topk_kernel<<<BB, 1024, 0, stream>>>(
        keys, cls, fusion_coords,
        out + OUT1_OFF, out + OUT4_OFF, tki, keyworld);

    knn_kernel<<<2 * BB * NK, 256, 0, stream>>>(
        src_feat_a, src_feat_b, gstart, pts, pidx,
        knn_w, knn_b, keyworld, mf);

    fuse_kernel<<<(BB * NK) / KPB, 1024, 0, stream>>>(
        fusion_feat, tki, kw_w1, kw_g1, kw_b1, kw_w2, kw_b2,
        fuse_w1, fuse_g1, fuse_b1, fuse_w2, fuse_b2, mf, out + OUT0_OFF);
}

// Round 10
// 244.272 us; speedup vs baseline: 1.2221x; 1.2221x over previous
//
#include <hip/hip_runtime.h>
#include <math.h>

#define BB 2
#define NF 20000
#define NS 30000
#define CH 128
#define NK 500
#define KNN 16
#define KPB 4

// grid params: cell = 1.001 * radius (margin vs float boundary rounding)
#define HA 2.4024f
#define HB 4.8048f
#define NCA 45
#define NCB 23
#define CELLS_A 2025
#define CELLS_B 529

// output offsets (floats, concatenated in return order)
#define OUT0_OFF 0           // out          (B*NK*128) = 128000
#define OUT1_OFF 128000      // key_voxel_indices (B*NK*3) = 3000
#define OUT2_OFF 131000      // heat_scores  (B*NF) = 40000
#define OUT3_OFF 171000      // scores10     (B*NF*10) = 400000
#define OUT4_OFF 571000      // key_class    (B*NK) = 1000

// workspace offsets (bytes)
#define WS_CLS   0           // int32  x 40000
#define WS_TKI   160000      // int32  x 1000
#define WS_KW    164000      // float  x 2000
#define WS_MF    172000      // float  x 256000 (1,024,000 B)
#define WS_KEYS  WS_MF       // u64 x 40000 overlays mf (temporally disjoint)
#define WS_GSTART 1196000    // int x 5112 (cell starts, +1 per (s,b))
#define WS_PTS    1236880    // float2 x 120000 (sorted world coords)
#define WS_PIDX   2196880    // int x 120000 (sorted original indices)

#define STB(s,b)  ((s) ? (4052 + (b) * 530) : ((b) * 2026))

__device__ __forceinline__ void fma4(float4& acc, float sc, const float4& wv) {
    acc.x += sc * wv.x; acc.y += sc * wv.y;
    acc.z += sc * wv.z; acc.w += sc * wv.w;
}

__device__ __forceinline__ unsigned ordf(float s) {
    unsigned u = __float_as_uint(s);
    return (u & 0x80000000u) ? ~u : (u | 0x80000000u);
}

__device__ __forceinline__ void world_cell_sb(
    const int2* sc, int s, int i, float& sx, float& sy, int& cell)
{
    int2 c = sc[i];
    float stride = s ? 8.0f : 4.0f;
    sx = __fadd_rn(__fmul_rn(__fmul_rn(__fadd_rn((float)c.x, 0.5f), stride), 0.075f), -54.0f);
    sy = __fadd_rn(__fmul_rn(__fmul_rn(__fadd_rn((float)c.y, 0.5f), stride), 0.075f), -54.0f);
    float inv_h = s ? (1.0f / HB) : (1.0f / HA);
    int nc = s ? NCB : NCA;
    int cx = (int)floorf((sx + 54.0f) * inv_h);
    int cy = (int)floorf((sy + 54.0f) * inv_h);
    cx = min(max(cx, 0), nc - 1);
    cy = min(max(cy, 0), nc - 1);
    cell = cy * nc + cx;
}

// ---------------------------------------------------------------------------
// K1: heat MLP, LDS-tiled SGEMM (pure 625-block form, reverted from R9).
// ---------------------------------------------------------------------------
__global__ __launch_bounds__(256) void heat_kernel(
    const float* __restrict__ x,
    const float* __restrict__ w1,
    const float* __restrict__ g1, const float* __restrict__ b1,
    const float* __restrict__ w2,
    const float* __restrict__ b2,
    float* __restrict__ out_heat,
    float* __restrict__ out_s10,
    int* __restrict__ cls,
    unsigned long long* __restrict__ keys)
{
    __shared__ float As[64 * 72];
    __shared__ float Ws[64 * 132];
    __shared__ float W2s[1280];
    const int tid = threadIdx.x;
    const int m0 = blockIdx.x * 64;
    const int tx = tid & 15;
    const int ty = tid >> 4;

    for (int v = tid; v < 1280; v += 256) W2s[v] = w2[v];

    float acc[4][8];
#pragma unroll
    for (int i = 0; i < 4; ++i)
#pragma unroll
        for (int j = 0; j < 8; ++j) acc[i][j] = 0.f;

    const float4* xv = (const float4*)x;
    const float4* w1v = (const float4*)w1;

    for (int kc = 0; kc < 128; kc += 64) {
#pragma unroll
        for (int i = 0; i < 4; ++i) {
            int v = tid + i * 256;
            int row = v >> 4, c4 = v & 15;
            float4 val = xv[(size_t)(m0 + row) * 32 + (kc >> 2) + c4];
            *(float4*)&As[row * 72 + c4 * 4] = val;
        }
#pragma unroll
        for (int i = 0; i < 8; ++i) {
            int v = tid + i * 256;
            int k = v >> 5, c4 = v & 31;
            float4 val = w1v[(size_t)(kc + k) * 32 + c4];
            *(float4*)&Ws[k * 132 + c4 * 4] = val;
        }
        __syncthreads();

        const float* a0p = &As[(ty * 4 + 0) * 72];
        const float* a1p = &As[(ty * 4 + 1) * 72];
        const float* a2p = &As[(ty * 4 + 2) * 72];
        const float* a3p = &As[(ty * 4 + 3) * 72];
#pragma unroll 4
        for (int k = 0; k < 64; ++k) {
            float4 bA = *(const float4*)&Ws[k * 132 + tx * 8];
            float4 bB = *(const float4*)&Ws[k * 132 + tx * 8 + 4];
            float a0 = a0p[k], a1 = a1p[k], a2 = a2p[k], a3 = a3p[k];
            acc[0][0] += a0 * bA.x; acc[0][1] += a0 * bA.y; acc[0][2] += a0 * bA.z; acc[0][3] += a0 * bA.w;
            acc[0][4] += a0 * bB.x; acc[0][5] += a0 * bB.y; acc[0][6] += a0 * bB.z; acc[0][7] += a0 * bB.w;
            acc[1][0] += a1 * bA.x; acc[1][1] += a1 * bA.y; acc[1][2] += a1 * bA.z; acc[1][3] += a1 * bA.w;
            acc[1][4] += a1 * bB.x; acc[1][5] += a1 * bB.y; acc[1][6] += a1 * bB.z; acc[1][7] += a1 * bB.w;
            acc[2][0] += a2 * bA.x; acc[2][1] += a2 * bA.y; acc[2][2] += a2 * bA.z; acc[2][3] += a2 * bA.w;
            acc[2][4] += a2 * bB.x; acc[2][5] += a2 * bB.y; acc[2][6] += a2 * bB.z; acc[2][7] += a2 * bB.w;
            acc[3][0] += a3 * bA.x; acc[3][1] += a3 * bA.y; acc[3][2] += a3 * bA.z; acc[3][3] += a3 * bA.w;
            acc[3][4] += a3 * bB.x; acc[3][5] += a3 * bB.y; acc[3][6] += a3 * bB.z; acc[3][7] += a3 * bB.w;
        }
        __syncthreads();
    }

    float4 g1a = ((const float4*)g1)[tx * 2], g1b = ((const float4*)g1)[tx * 2 + 1];
    float4 b1a = ((const float4*)b1)[tx * 2], b1b = ((const float4*)b1)[tx * 2 + 1];
    float* Hs = Ws;
#pragma unroll
    for (int i = 0; i < 4; ++i) {
        int row = ty * 4 + i;
        float4 hA, hB;
        hA.x = fmaxf(acc[i][0] * g1a.x + b1a.x, 0.f);
        hA.y = fmaxf(acc[i][1] * g1a.y + b1a.y, 0.f);
        hA.z = fmaxf(acc[i][2] * g1a.z + b1a.z, 0.f);
        hA.w = fmaxf(acc[i][3] * g1a.w + b1a.w, 0.f);
        hB.x = fmaxf(acc[i][4] * g1b.x + b1b.x, 0.f);
        hB.y = fmaxf(acc[i][5] * g1b.y + b1b.y, 0.f);
        hB.z = fmaxf(acc[i][6] * g1b.z + b1b.z, 0.f);
        hB.w = fmaxf(acc[i][7] * g1b.w + b1b.w, 0.f);
        *(float4*)&Hs[row * 132 + tx * 8] = hA;
        *(float4*)&Hs[row * 132 + tx * 8 + 4] = hB;
    }
    __syncthreads();

    const int r = tid >> 2;
    const int p = tid & 3;
    float a2[10];
#pragma unroll
    for (int c = 0; c < 10; ++c) a2[c] = 0.f;
    for (int kk = 0; kk < 32; ++kk) {
        int k = kk * 4 + p;
        float hv = Hs[r * 132 + k];
#pragma unroll
        for (int c = 0; c < 10; ++c) a2[c] += hv * W2s[k * 10 + c];
    }
#pragma unroll
    for (int c = 0; c < 10; ++c) {
        a2[c] += __shfl_xor(a2[c], 1);
        a2[c] += __shfl_xor(a2[c], 2);
    }
    if (p == 0) {
        int m = m0 + r;
        float best = -INFINITY;
        int bi = 0;
#pragma unroll
        for (int c = 0; c < 10; ++c) {
            float s = a2[c] + b2[c];
            out_s10[(size_t)m * 10 + c] = s;
            if (s > best) { best = s; bi = c; }
        }
        out_heat[m] = best;
        cls[m] = bi;
        int b = m / NF;
        unsigned i = (unsigned)(m - b * NF);
        float sig = 1.0f / (1.0f + expf(-best));
        keys[m] = ((unsigned long long)ordf(sig) << 32) | (unsigned)(~i);
    }
}

// ---------------------------------------------------------------------------
// K2 "mid": blocks 0-1 = fast topk (suffix-scan threshold + rank-by-compare);
// blocks 2-5 = spatial grid build at 1024 threads (back from R9's 256-thread
// tail, which serialized behind heat).
// ---------------------------------------------------------------------------
#define H1BINS 16384

__global__ __launch_bounds__(1024) void mid_kernel(
    const unsigned long long* __restrict__ keys,
    const int* __restrict__ cls,
    const int* __restrict__ fcoords,
    float* __restrict__ out1,
    float* __restrict__ out4,
    int* __restrict__ tki,
    float* __restrict__ keyworld,
    const int* __restrict__ sca, const int* __restrict__ scb,
    int* __restrict__ gstart,
    float2* __restrict__ pts, int* __restrict__ pidx)
{
    __shared__ unsigned h[H1BINS];            // 64 KB
    __shared__ unsigned sA[1024], sB[1024];   // 8 KB scan buffers
    __shared__ unsigned long long list[1024]; // 8 KB
    __shared__ unsigned chunk_s, aboveC_s, T1_s, aboveT1_s, cand_s, thr_s, cnt_s;
    __shared__ int ghist[2048];
    const int tid = threadIdx.x;
    const int blk = blockIdx.x;

    if (blk >= 2) {
        // ---- grid build for (s,b), 1024 threads ----
        const int g = blk - 2;
        const int s = g >> 1, b = g & 1;
        const int n = s ? CELLS_B : CELLS_A;
        const int stb = STB(s, b);
        const int2* sc = ((const int2*)(s ? scb : sca)) + (size_t)b * NS;
        const size_t pbase = ((size_t)s * BB + b) * NS;
        int* gt0 = (int*)sA;
        int* gt1 = (int*)sB;

        for (int i = tid; i < 2048; i += 1024) ghist[i] = 0;
        __syncthreads();
        for (int i = tid; i < NS; i += 1024) {
            float sx, sy; int cell;
            world_cell_sb(sc, s, i, sx, sy, cell);
            atomicAdd(&ghist[cell], 1);
        }
        __syncthreads();
        int i0 = tid * 2, i1 = tid * 2 + 1;
        int c0 = (i0 < n) ? ghist[i0] : 0;
        int c1 = (i1 < n) ? ghist[i1] : 0;
        gt0[tid] = c0 + c1;
        __syncthreads();
        int* srcp = gt0; int* dstp = gt1;
        for (int off = 1; off < 1024; off <<= 1) {
            int v = srcp[tid];
            if (tid >= off) v += srcp[tid - off];
            dstp[tid] = v;
            __syncthreads();
            int* t = srcp; srcp = dstp; dstp = t;
        }
        int excl = (tid == 0) ? 0 : srcp[tid - 1];
        if (i0 < n) { gstart[stb + i0] = excl; ghist[i0] = excl; }
        if (i1 < n) { gstart[stb + i1] = excl + c0; ghist[i1] = excl + c0; }
        if (tid == 0) gstart[stb + n] = NS;
        __syncthreads();
        for (int i = tid; i < NS; i += 1024) {
            float sx, sy; int cell;
            world_cell_sb(sc, s, i, sx, sy, cell);
            int pos = atomicAdd(&ghist[cell], 1);
            pts[pbase + pos] = make_float2(sx, sy);
            pidx[pbase + pos] = i;
        }
        return;
    }

    // ---- topk for batch b = blk ----
    const int b = blk;
    const unsigned long long* kb = keys + (size_t)b * NF;
    const unsigned K = NK;

    for (int i = tid; i < H1BINS; i += 1024) h[i] = 0u;
    __syncthreads();
#pragma unroll 4
    for (int i = tid; i < NF; i += 1024)
        atomicAdd(&h[(unsigned)(kb[i] >> 50)], 1u);
    __syncthreads();
    unsigned ck = 0;
    {
        int base = tid * 16;
#pragma unroll
        for (int j = 0; j < 16; ++j) ck += h[base + j];
        sA[tid] = ck;
    }
    __syncthreads();
    // inclusive suffix scan over 1024 chunk sums
    unsigned* srcp = sA; unsigned* dstp = sB;
    for (int off = 1; off < 1024; off <<= 1) {
        unsigned v = srcp[tid];
        if (tid + off < 1024) v += srcp[tid + off];
        dstp[tid] = v;
        __syncthreads();
        unsigned* t = srcp; srcp = dstp; dstp = t;
    }
    {
        unsigned suf = srcp[tid];
        unsigned above = suf - ck;
        if (above < K && K <= suf) { chunk_s = (unsigned)tid; aboveC_s = above; }
    }
    __syncthreads();
    if (tid == 0) {
        int bin = (int)chunk_s * 16 + 15;
        unsigned acc = aboveC_s;
        for (;; --bin) { if (acc + h[bin] >= K) break; acc += h[bin]; }
        T1_s = (unsigned)bin;
        aboveT1_s = acc;
        cand_s = acc + h[bin];
        cnt_s = 0u;
    }
    __syncthreads();
    const unsigned T1 = T1_s;

    if (cand_s <= 1024u) {
        // direct collect with 14-bit threshold (the common path)
#pragma unroll 4
        for (int i = tid; i < NF; i += 1024) {
            unsigned long long key = kb[i];
            if ((unsigned)(key >> 50) >= T1) {
                unsigned pos = atomicAdd(&cnt_s, 1u);
                if (pos < 1024u) list[pos] = key;
            }
        }
    } else {
        // fallback: refine to 24-bit threshold (rare: >1024 keys in one bin)
        const unsigned K2 = K - aboveT1_s;
        h[tid] = 0u;
        __syncthreads();
#pragma unroll 4
        for (int i = tid; i < NF; i += 1024) {
            unsigned long long key = kb[i];
            if ((unsigned)(key >> 50) == T1)
                atomicAdd(&h[(unsigned)(key >> 40) & 1023u], 1u);
        }
        __syncthreads();
        unsigned hb = h[tid];
        sA[tid] = hb;
        __syncthreads();
        unsigned* s2 = sA; unsigned* d2 = sB;
        for (int off = 1; off < 1024; off <<= 1) {
            unsigned v = s2[tid];
            if (tid + off < 1024) v += s2[tid + off];
            d2[tid] = v;
            __syncthreads();
            unsigned* t = s2; s2 = d2; d2 = t;
        }
        {
            unsigned suf = s2[tid];
            unsigned above = suf - hb;
            if (above < K2 && K2 <= suf) thr_s = (T1 << 10) | (unsigned)tid;
        }
        __syncthreads();
        const unsigned thr24 = thr_s;
#pragma unroll 4
        for (int i = tid; i < NF; i += 1024) {
            unsigned long long key = kb[i];
            if ((unsigned)(key >> 40) >= thr24) {
                unsigned pos = atomicAdd(&cnt_s, 1u);
                if (pos < 1024u) list[pos] = key;
            }
        }
    }
    __syncthreads();
    const int cc = (int)(cnt_s > 1024u ? 1024u : cnt_s);

    // exhaustive ranking: keys unique -> exact permutation, no barriers
    if (tid < cc) {
        unsigned long long mykey = list[tid];
        unsigned r = 0;
#pragma unroll 8
        for (int j = 0; j < cc; ++j) r += (list[j] > mykey) ? 1u : 0u;
        if (r < (unsigned)NK) {
            int idx = (int)(~(unsigned)(mykey & 0xFFFFFFFFull));
            tki[b * NK + (int)r] = idx;
            int c0 = fcoords[((size_t)b * NF + idx) * 2 + 0];
            int c1 = fcoords[((size_t)b * NF + idx) * 2 + 1];
            size_t o = (size_t)(b * NK + (int)r);
            out1[o * 3 + 0] = (float)b;
            out1[o * 3 + 1] = (float)c0;
            out1[o * 3 + 2] = (float)c1;
            float wx = __fadd_rn(__fmul_rn(__fmul_rn(__fadd_rn((float)c0, 0.5f), 8.0f), 0.075f), -54.0f);
            float wy = __fadd_rn(__fmul_rn(__fmul_rn(__fadd_rn((float)c1, 0.5f), 8.0f), 0.075f), -54.0f);
            keyworld[o * 2 + 0] = wx;
            keyworld[o * 2 + 1] = wy;
            out4[o] = (float)cls[(size_t)b * NF + idx];
        }
    }
}

// ---------------------------------------------------------------------------
// K3: grid-accelerated radius-KNN (unchanged).
// ---------------------------------------------------------------------------
__global__ __launch_bounds__(256) void knn_kernel(
    const float* __restrict__ sfa, const float* __restrict__ sfb,
    const int* __restrict__ gstart,
    const float2* __restrict__ pts, const int* __restrict__ pidx,
    const float* __restrict__ knn_w,
    const float* __restrict__ knn_b,
    const float* __restrict__ keyworld,
    float* __restrict__ mf)
{
    __shared__ unsigned long long list[1024];
    __shared__ float psum[128];
    __shared__ unsigned cnt_s;
    const int tid = threadIdx.x;
    const int blk = blockIdx.x;
    const int s = blk / (BB * NK);
    const int rest = blk % (BB * NK);
    const int b = rest / NK;
    const int r = rest % NK;
    const float* sfeat = s ? sfb : sfa;
    const float r2 = s ? (float)(4.8 * 4.8) : (float)(2.4 * 2.4);
    const float inv_h = s ? (1.0f / HB) : (1.0f / HA);
    const int nc = s ? NCB : NCA;
    const int stb = STB(s, b);
    const size_t pbase = ((size_t)s * BB + b) * NS;

    if (tid == 0) cnt_s = 0u;
    __syncthreads();
    const float kx = keyworld[((size_t)b * NK + r) * 2 + 0];
    const float ky = keyworld[((size_t)b * NK + r) * 2 + 1];
    int cx = (int)floorf((kx + 54.0f) * inv_h);
    int cy = (int)floorf((ky + 54.0f) * inv_h);
    cx = min(max(cx, 0), nc - 1);
    cy = min(max(cy, 0), nc - 1);
    const int c0 = max(cx - 1, 0), c1 = min(cx + 1, nc - 1);
    const int cy0 = max(cy - 1, 0), cy1 = min(cy + 1, nc - 1);

    for (int cyy = cy0; cyy <= cy1; ++cyy) {
        int lo = gstart[stb + cyy * nc + c0];
        int hi = gstart[stb + cyy * nc + c1 + 1];
        for (int p = lo + tid; p < hi; p += 256) {
            float2 w = pts[pbase + p];
            float dx = __fsub_rn(kx, w.x);
            float dy = __fsub_rn(ky, w.y);
            float d2 = __fadd_rn(__fmul_rn(dx, dx), __fmul_rn(dy, dy));
            if (d2 <= r2) {
                unsigned pos = atomicAdd(&cnt_s, 1u);
                if (pos < 1024u)
                    list[pos] = ((unsigned long long)__float_as_uint(d2) << 32)
                              | (unsigned)pidx[pbase + p];
            }
        }
    }
    __syncthreads();
    int cc = (int)cnt_s;
    if (cc > 1024) cc = 1024;
    int n2 = 16;
    while (n2 < cc) n2 <<= 1;
    for (int i = tid; i < n2; i += 256)
        if (i >= cc) list[i] = ~0ull;
    __syncthreads();
    for (int kk = 2; kk <= n2; kk <<= 1) {
        for (int j = kk >> 1; j > 0; j >>= 1) {
            for (int i = tid; i < n2; i += 256) {
                int ixj = i ^ j;
                if (ixj > i) {
                    unsigned long long a = list[i], bv = list[ixj];
                    bool up = ((i & kk) == 0);
                    bool sw = up ? (a > bv) : (a < bv);
                    if (sw) { list[i] = bv; list[ixj] = a; }
                }
            }
            __syncthreads();
        }
    }
    {
        int K = cc < KNN ? cc : KNN;
        int col = tid & 127, half = tid >> 7;
        float acc = 0.f;
        int k0 = half * 8, k1 = min(K, half * 8 + 8);
        for (int k = k0; k < k1; ++k) {
            unsigned i = (unsigned)(list[k] & 0xFFFFFFFFull);
            acc += knn_w[s * 16 + k] * sfeat[((size_t)b * NS + i) * CH + col];
        }
        if (half) psum[col] = acc;
        __syncthreads();
        if (!half)
            mf[(((size_t)s * BB + b) * NK + r) * CH + col] = knn_b[s] + acc + psum[col];
    }
}

// ---------------------------------------------------------------------------
// K4: fuse MLP (unchanged from R8: direct L2-resident float4 weight loads,
// 8-16 in flight, transposed activations, split-K tree reduce).
// ---------------------------------------------------------------------------
__global__ __launch_bounds__(1024) void fuse_kernel(
    const float* __restrict__ ffeat,
    const int* __restrict__ tki,
    const float* __restrict__ kw_w1, const float* __restrict__ kw_g1,
    const float* __restrict__ kw_b1, const float* __restrict__ kw_w2,
    const float* __restrict__ kw_b2,
    const float* __restrict__ fuse_w1, const float* __restrict__ fuse_g1,
    const float* __restrict__ fuse_b1, const float* __restrict__ fuse_w2,
    const float* __restrict__ fuse_b2,
    const float* __restrict__ mf,
    float* __restrict__ out0)
{
    __shared__ float pL[16384];     // 64 KB split-K partials
    __shared__ float xsT[512];      // x transposed [k][key]
    __shared__ float mfs[1024];     // [src][key][c]
    __shared__ float fusedvT[1024]; // [k][key]
    __shared__ float h2sT[1024];    // [k][key]
    __shared__ float prm[964];      // kw_g1|kw_b1|kw_w2|kw_b2|fg1|fb1|fb2
    __shared__ float hsX[256];      // kw hidden [key][k]
    __shared__ float p2[96];
    __shared__ float l3[12];
    __shared__ float wsm[8];
    __shared__ int idxs[KPB], bs[KPB], rs[KPB];
    const int tid = threadIdx.x;
    const int f0 = blockIdx.x * KPB;

    if (tid < 964) {
        float v;
        if (tid < 64)       v = kw_g1[tid];
        else if (tid < 128) v = kw_b1[tid - 64];
        else if (tid < 320) v = kw_w2[tid - 128];
        else if (tid < 323) v = kw_b2[tid - 320];
        else if (tid < 324) v = 0.f;
        else if (tid < 580) v = fuse_g1[tid - 324];
        else if (tid < 836) v = fuse_b1[tid - 580];
        else                v = fuse_b2[tid - 836];
        prm[tid] = v;
    }
    if (tid < KPB) {
        int flat = f0 + tid;
        int b = flat / NK;
        bs[tid] = b;
        rs[tid] = flat - b * NK;
        idxs[tid] = tki[flat];
    }
    __syncthreads();

    if (tid < 128) {
        int key = tid >> 5, c4 = tid & 31;
        float4 v = ((const float4*)(ffeat + ((size_t)bs[key] * NF + idxs[key]) * CH))[c4];
        xsT[(c4 * 4 + 0) * 4 + key] = v.x;
        xsT[(c4 * 4 + 1) * 4 + key] = v.y;
        xsT[(c4 * 4 + 2) * 4 + key] = v.z;
        xsT[(c4 * 4 + 3) * 4 + key] = v.w;
    }
    if (tid < 256) {
        int ss = tid >> 7, key = (tid >> 5) & 3, c4 = tid & 31;
        float4 v = ((const float4*)(mf + (((size_t)ss * BB + bs[key]) * NK + rs[key]) * CH))[c4];
        *(float4*)&mfs[ss * 512 + key * 128 + c4 * 4] = v;
    }
    __syncthreads();

    if (tid < 256) {
        const int og = tid & 15, kseg = tid >> 4;
        float4 wr[8];
#pragma unroll
        for (int m = 0; m < 8; ++m)
            wr[m] = ((const float4*)kw_w1)[(kseg * 8 + m) * 16 + og];
        float4 a0 = {0, 0, 0, 0}, a1 = {0, 0, 0, 0}, a2 = {0, 0, 0, 0}, a3 = {0, 0, 0, 0};
#pragma unroll
        for (int m = 0; m < 8; ++m) {
            float4 f4 = *(const float4*)&xsT[(kseg * 8 + m) * 4];
            fma4(a0, f4.x, wr[m]);
            fma4(a1, f4.y, wr[m]);
            fma4(a2, f4.z, wr[m]);
            fma4(a3, f4.w, wr[m]);
        }
        *(float4*)&pL[(kseg * 4 + 0) * 64 + og * 4] = a0;
        *(float4*)&pL[(kseg * 4 + 1) * 64 + og * 4] = a1;
        *(float4*)&pL[(kseg * 4 + 2) * 64 + og * 4] = a2;
        *(float4*)&pL[(kseg * 4 + 3) * 64 + og * 4] = a3;
    }
    __syncthreads();
    if (tid < 256) {
        int out = tid >> 2, key = tid & 3;
        float s = 0.f;
#pragma unroll
        for (int ks = 0; ks < 16; ++ks) s += pL[(ks * 4 + key) * 64 + out];
        float t = s * prm[out] + prm[64 + out];
        hsX[key * 64 + out] = t > 0.f ? t : 0.f;
    }
    __syncthreads();
    if (tid < 96) {
        int key = tid / 24, rr = tid % 24, out = rr >> 3, seg = rr & 7;
        float acc = 0.f;
#pragma unroll
        for (int m = 0; m < 8; ++m) {
            int k = seg * 8 + m;
            acc += hsX[key * 64 + k] * prm[128 + k * 3 + out];
        }
        p2[(key * 3 + out) * 8 + seg] = acc;
    }
    __syncthreads();
    if (tid < 12) {
        int key = tid / 3, out = tid % 3;
        float s = 0.f;
#pragma unroll
        for (int j = 0; j < 8; ++j) s += p2[(key * 3 + out) * 8 + j];
        l3[key * 3 + out] = s + prm[320 + out];
    }
    __syncthreads();
    if (tid < KPB) {
        float l0 = l3[tid * 3], l1 = l3[tid * 3 + 1], l2 = l3[tid * 3 + 2];
        float m = fmaxf(l0, fmaxf(l1, l2));
        float e0 = expf(l0 - m), e1 = expf(l1 - m), e2 = expf(l2 - m);
        float sum = e0 + e1 + e2;
        wsm[tid * 2 + 0] = e0 / sum;
        wsm[tid * 2 + 1] = e1 / sum;
    }
    __syncthreads();

    {
        int c = tid >> 2, key = tid & 3;
        float w0 = wsm[key * 2], w1_ = wsm[key * 2 + 1];
        float val;
        if (c < 128) {
            float xv_ = xsT[c * 4 + key];
            float m0 = mfs[key * 128 + c];
            float m1 = mfs[512 + key * 128 + c];
            float kv = w0 * xv_;
            float kv2 = w1_ * kv;
            val = kv * m0 + kv2 * m1;
        } else {
            float xv_ = xsT[(c - 128) * 4 + key];
            val = w1_ * (w0 * xv_);
        }
        fusedvT[tid] = val;
    }
    __syncthreads();

    {
        const int og = tid & 63, kseg = tid >> 6;
        const float4* w1v = (const float4*)fuse_w1;
        float4 wr[16];
#pragma unroll
        for (int m = 0; m < 16; ++m)
            wr[m] = w1v[(kseg * 16 + m) * 64 + og];
        float4 a0 = {0, 0, 0, 0}, a1 = {0, 0, 0, 0}, a2 = {0, 0, 0, 0}, a3 = {0, 0, 0, 0};
#pragma unroll
        for (int m = 0; m < 16; ++m) {
            float4 f4 = *(const float4*)&fusedvT[(kseg * 16 + m) * 4];
            fma4(a0, f4.x, wr[m]);
            fma4(a1, f4.y, wr[m]);
            fma4(a2, f4.z, wr[m]);
            fma4(a3, f4.w, wr[m]);
        }
        *(float4*)&pL[(kseg * 4 + 0) * 256 + og * 4] = a0;
        *(float4*)&pL[(kseg * 4 + 1) * 256 + og * 4] = a1;
        *(float4*)&pL[(kseg * 4 + 2) * 256 + og * 4] = a2;
        *(float4*)&pL[(kseg * 4 + 3) * 256 + og * 4] = a3;
    }
    __syncthreads();
    {
        int out = tid >> 2, key = tid & 3;
        float s = 0.f;
#pragma unroll
        for (int ks = 0; ks < 16; ++ks) s += pL[(ks * 4 + key) * 256 + out];
        float t = s * prm[324 + out] + prm[580 + out];
        h2sT[out * 4 + key] = t > 0.f ? t : 0.f;
    }
    __syncthreads();

    {
        const int og2 = tid & 31, kseg2 = tid >> 5;
        const float4* w2v = (const float4*)fuse_w2;
        float4 wr[8];
#pragma unroll
        for (int m = 0; m < 8; ++m)
            wr[m] = w2v[(kseg2 * 8 + m) * 32 + og2];
        float4 a0 = {0, 0, 0, 0}, a1 = {0, 0, 0, 0}, a2 = {0, 0, 0, 0}, a3 = {0, 0, 0, 0};
#pragma unroll
        for (int m = 0; m < 8; ++m) {
            float4 f4 = *(const float4*)&h2sT[(kseg2 * 8 + m) * 4];
            fma4(a0, f4.x, wr[m]);
            fma4(a1, f4.y, wr[m]);
            fma4(a2, f4.z, wr[m]);
            fma4(a3, f4.w, wr[m]);
        }
        *(float4*)&pL[(kseg2 * 4 + 0) * 128 + og2 * 4] = a0;
        *(float4*)&pL[(kseg2 * 4 + 1) * 128 + og2 * 4] = a1;
        *(float4*)&pL[(kseg2 * 4 + 2) * 128 + og2 * 4] = a2;
        *(float4*)&pL[(kseg2 * 4 + 3) * 128 + og2 * 4] = a3;
    }
    __syncthreads();
    if (tid < 512) {
        int out = tid >> 2, key = tid & 3;
        float s = prm[836 + out];
#pragma unroll
        for (int ks = 0; ks < 32; ++ks) s += pL[(ks * 4 + key) * 128 + out];
        out0[((size_t)bs[key] * NK + rs[key]) * CH + out] = s;
    }
}

extern "C" void kernel_launch(void* const* d_in, const int* in_sizes, int n_in,
                              void* d_out, int out_size, void* d_ws, size_t ws_size,
                              hipStream_t stream)
{
    const float* fusion_feat = (const float*)d_in[0];
    const float* src_feat_a  = (const float*)d_in[1];
    const float* src_feat_b  = (const float*)d_in[2];
    const float* heat_w1 = (const float*)d_in[3];
    const float* heat_g1 = (const float*)d_in[4];
    const float* heat_b1 = (const float*)d_in[5];
    const float* heat_w2 = (const float*)d_in[6];
    const float* heat_b2 = (const float*)d_in[7];
    const float* knn_w   = (const float*)d_in[8];
    const float* knn_b   = (const float*)d_in[9];
    const float* kw_w1   = (const float*)d_in[10];
    const float* kw_g1   = (const float*)d_in[11];
    const float* kw_b1   = (const float*)d_in[12];
    const float* kw_w2   = (const float*)d_in[13];
    const float* kw_b2   = (const float*)d_in[14];
    const float* fuse_w1 = (const float*)d_in[15];
    const float* fuse_g1 = (const float*)d_in[16];
    const float* fuse_b1 = (const float*)d_in[17];
    const float* fuse_w2 = (const float*)d_in[18];
    const float* fuse_b2 = (const float*)d_in[19];
    const int* fusion_coords = (const int*)d_in[20];
    const int* src_coords_a  = (const int*)d_in[21];
    const int* src_coords_b  = (const int*)d_in[22];

    float* out = (float*)d_out;
    char* ws = (char*)d_ws;
    int* cls = (int*)(ws + WS_CLS);
    int* tki = (int*)(ws + WS_TKI);
    float* keyworld = (float*)(ws + WS_KW);
    float* mf = (float*)(ws + WS_MF);
    unsigned long long* keys = (unsigned long long*)(ws + WS_KEYS);
    int* gstart = (int*)(ws + WS_GSTART);
    float2* pts = (float2*)(ws + WS_PTS);
    int* pidx = (int*)(ws + WS_PIDX);

    heat_kernel<<<(BB * NF) / 64, 256, 0, stream>>>(
        fusion_feat, heat_w1, heat_g1, heat_b1, heat_w2, heat_b2,
        out + OUT2_OFF, out + OUT3_OFF, cls, keys);

    mid_kernel<<<6, 1024, 0, stream>>>(
        keys, cls, fusion_coords,
        out + OUT1_OFF, out + OUT4_OFF, tki, keyworld,
        src_coords_a, src_coords_b, gstart, pts, pidx);

    knn_kernel<<<2 * BB * NK, 256, 0, stream>>>(
        src_feat_a, src_feat_b, gstart, pts, pidx,
        knn_w, knn_b, keyworld, mf);

    fuse_kernel<<<(BB * NK) / KPB, 1024, 0, stream>>>(
        fusion_feat, tki, kw_w1, kw_g1, kw_b1, kw_w2, kw_b2,
        fuse_w1, fuse_g1, fuse_b1, fuse_w2, fuse_b2, mf, out + OUT0_OFF);
}